// Round 2
// baseline (139.946 us; speedup 1.0000x reference)
//
#include <hip/hip_runtime.h>

#define D_MODEL 1024
#define ADAPT   128
#define NUM_LIB 8
#define BATCH   1024
#define CH      16
#define NSLOT   128

typedef __attribute__((ext_vector_type(8))) short bf16x8;
typedef __attribute__((ext_vector_type(4))) float f32x4;

__device__ __forceinline__ short f2bf(float f) {
  unsigned u = __float_as_uint(f);
  u += 0x7FFFu + ((u >> 16) & 1u);   // RNE to bf16
  return (short)(u >> 16);
}

// ---------------------------------------------------------------------------
// Kernel 1: bucket samples by pair, build CSR perm + chunk table in ws.
// ---------------------------------------------------------------------------
__global__ __launch_bounds__(1024) void bucket_k(const int* __restrict__ src,
                                                 const int* __restrict__ tgt,
                                                 int* __restrict__ perm,
                                                 int* __restrict__ cpair,
                                                 int* __restrict__ cbase,
                                                 int* __restrict__ cm) {
  __shared__ int cnt[64];
  __shared__ int offs[64];
  __shared__ int pos[64];
  int t = threadIdx.x;
  if (t < 64) { cnt[t] = 0; pos[t] = 0; }
  __syncthreads();
  int pair = src[t] * NUM_LIB + tgt[t];
  atomicAdd(&cnt[pair], 1);
  __syncthreads();
  if (t == 0) {
    int acc = 0;
    for (int i = 0; i < 64; i++) { offs[i] = acc; acc += cnt[i]; }
  }
  __syncthreads();
  int sl = atomicAdd(&pos[pair], 1);
  perm[offs[pair] + sl] = t;
  if (t == 0) {
    int nc = 0;
    for (int p = 0; p < 64; p++) {
      for (int c0 = 0; c0 < cnt[p]; c0 += CH) {
        cpair[nc] = p;
        cbase[nc] = offs[p] + c0;
        cm[nc]    = min(CH, cnt[p] - c0);
        nc++;
      }
    }
    for (; nc < NSLOT; nc++) cpair[nc] = -1;
  }
}

// ---------------------------------------------------------------------------
// Kernel 2: H[rows,:] = relu(X[rows,:] @ W1[p] + b1[p]) per chunk, bf16 MFMA.
// grid = (NSLOT, 2): blockIdx.y selects a-half (64 of 128 adapter dims).
// ---------------------------------------------------------------------------
#define XS_STR 1032   // 1024 + 8 pad (shorts) -> bank-floor A-frag reads
#define WT_STR 136    // 128 + 8 pad (shorts)

__global__ __launch_bounds__(256) void gemm1_k(const float* __restrict__ x,
                                               const float* __restrict__ W1,
                                               const float* __restrict__ b1,
                                               const int* __restrict__ perm,
                                               const int* __restrict__ cpair,
                                               const int* __restrict__ cbase,
                                               const int* __restrict__ cm,
                                               float* __restrict__ H) {
  int slot = blockIdx.x;
  int p = cpair[slot];
  if (p < 0 || (p % 9) == 0) return;   // empty slot or diagonal (identity)
  int m    = cm[slot];
  int base = cbase[slot];
  int a0   = blockIdx.y * 64;
  __shared__ int   rows_s[CH];
  __shared__ short xs[CH * XS_STR];    // X chunk, bf16 [s][k]
  __shared__ short wt[64 * WT_STR];    // W1 tile,  bf16 [a][k] (transposed)
  int t = threadIdx.x;
  if (t < CH) rows_s[t] = perm[base + min(t, m - 1)];
  __syncthreads();
  // Stage full X chunk (16 x 1024) fp32 -> bf16, natural [s][k] layout.
  {
    int s = t & 15, jg = t >> 4;       // thread: row s, k-range jg*64..+63
    const float* xr = x + (size_t)rows_s[s] * D_MODEL + jg * 64;
    short* xw = xs + s * XS_STR + jg * 64;
#pragma unroll
    for (int i = 0; i < 16; i++) {
      float4 v = *(const float4*)(xr + i * 4);
      short4 o;
      o.x = f2bf(v.x); o.y = f2bf(v.y); o.z = f2bf(v.z); o.w = f2bf(v.w);
      *(short4*)(xw + i * 4) = o;
    }
  }
  int lane = t & 63;
  int wvid = t >> 6;                   // wave -> N-tile (16 a's)
  int col  = lane & 15;
  int quad = lane >> 4;
  f32x4 acc = {0.f, 0.f, 0.f, 0.f};
  int a_st = t & 63, kg = t >> 6;      // staging role: a-lane, k-group
  for (int k0 = 0; k0 < D_MODEL; k0 += 128) {
    {  // stage W1[k0..k0+127][a0..a0+63] -> wt[a][k] bf16 (transpose+cvt)
      const float* wr = W1 + ((size_t)p * D_MODEL + k0 + kg * 32) * ADAPT + a0 + a_st;
      short* ww = wt + a_st * WT_STR + kg * 32;
#pragma unroll
      for (int ii = 0; ii < 4; ii++) {
        bf16x8 o;
#pragma unroll
        for (int i = 0; i < 8; i++) o[i] = f2bf(wr[(ii * 8 + i) * ADAPT]);
        *(bf16x8*)(ww + ii * 8) = o;
      }
    }
    __syncthreads();
#pragma unroll
    for (int kk = 0; kk < 4; kk++) {
      bf16x8 af = *(const bf16x8*)(xs + col * XS_STR + k0 + kk * 32 + quad * 8);
      bf16x8 bv = *(const bf16x8*)(wt + (wvid * 16 + col) * WT_STR + kk * 32 + quad * 8);
      acc = __builtin_amdgcn_mfma_f32_16x16x32_bf16(af, bv, acc, 0, 0, 0);
    }
    __syncthreads();
  }
  // Epilogue: bias + relu in fp32; D layout col=lane&15 (a), row=quad*4+reg (s).
  int a = a0 + wvid * 16 + col;
  float bb = b1[p * ADAPT + a];
#pragma unroll
  for (int r = 0; r < 4; r++) {
    int s = quad * 4 + r;
    if (s < m) H[(size_t)rows_s[s] * ADAPT + a] = fmaxf(acc[r] + bb, 0.f);
  }
}

// ---------------------------------------------------------------------------
// Kernel 3: out[rows, d0..d0+127] = H[rows,:] @ W2[p][:, d0..] + b2  (or copy x
// for diagonal pairs). grid = (NSLOT, 8).
// ---------------------------------------------------------------------------
#define HS_STR  136
#define WT2_STR 136

__global__ __launch_bounds__(256) void gemm2_k(const float* __restrict__ x,
                                               const float* __restrict__ W2,
                                               const float* __restrict__ b2,
                                               const int* __restrict__ perm,
                                               const int* __restrict__ cpair,
                                               const int* __restrict__ cbase,
                                               const int* __restrict__ cm,
                                               const float* __restrict__ H,
                                               float* __restrict__ out) {
  int slot = blockIdx.x;
  int p = cpair[slot];
  if (p < 0) return;
  int m    = cm[slot];
  int base = cbase[slot];
  int d0   = blockIdx.y * 128;
  __shared__ int rows_s[CH];
  int t = threadIdx.x;
  if (t < CH) rows_s[t] = perm[base + min(t, m - 1)];
  __syncthreads();
  if ((p % 9) == 0) {                  // identity: exact copy x -> out
    int s = t >> 4, j = t & 15;
    if (s < m) {
      size_t off = (size_t)rows_s[s] * D_MODEL + d0 + j * 8;
      float4 v0 = *(const float4*)(x + off);
      float4 v1 = *(const float4*)(x + off + 4);
      *(float4*)(out + off)     = v0;
      *(float4*)(out + off + 4) = v1;
    }
    return;
  }
  __shared__ short hs[CH * HS_STR];     // H chunk bf16 [s][k]
  __shared__ short wt[128 * WT2_STR];   // W2 slice bf16 [d][k] (transposed)
  {  // stage H chunk (16 x 128) fp32 -> bf16
    int s = t & 15, j = t >> 4;        // k-range j*8..+7
    const float* hr = H + (size_t)rows_s[s] * ADAPT + j * 8;
    float4 v0 = *(const float4*)hr;
    float4 v1 = *(const float4*)(hr + 4);
    bf16x8 o;
    o[0] = f2bf(v0.x); o[1] = f2bf(v0.y); o[2] = f2bf(v0.z); o[3] = f2bf(v0.w);
    o[4] = f2bf(v1.x); o[5] = f2bf(v1.y); o[6] = f2bf(v1.z); o[7] = f2bf(v1.w);
    *(bf16x8*)(hs + s * HS_STR + j * 8) = o;
  }
  {  // stage W2[0..127][d0..d0+127] -> wt[d][k] bf16 (transpose+cvt)
    // 2 threads per d (half=0/1); each stages 8 k's per iter; union covers
    // k in [0,128): half=0 -> {0-7,16-23,...}, half=1 -> {8-15,24-31,...}.
    int dl = t & 127, half = t >> 7;
#pragma unroll
    for (int kgi = 0; kgi < 8; kgi++) {
      int kb = kgi * 16 + half * 8;
      const float* wr = W2 + ((size_t)p * ADAPT + kb) * D_MODEL + d0 + dl;
      bf16x8 o;
#pragma unroll
      for (int i = 0; i < 8; i++) o[i] = f2bf(wr[i * D_MODEL]);
      *(bf16x8*)(wt + dl * WT2_STR + kb) = o;
    }
  }
  __syncthreads();
  int lane = t & 63, wvid = t >> 6, col = lane & 15, quad = lane >> 4;
  f32x4 acc0 = {0.f, 0.f, 0.f, 0.f};
  f32x4 acc1 = {0.f, 0.f, 0.f, 0.f};
  // wave wvid handles d-tiles (wvid*32) and (wvid*32+16)
#pragma unroll
  for (int kk = 0; kk < 4; kk++) {
    bf16x8 af = *(const bf16x8*)(hs + col * HS_STR + kk * 32 + quad * 8);
    bf16x8 b0 = *(const bf16x8*)(wt + (wvid * 32 + col) * WT2_STR + kk * 32 + quad * 8);
    bf16x8 b1v = *(const bf16x8*)(wt + (wvid * 32 + 16 + col) * WT2_STR + kk * 32 + quad * 8);
    acc0 = __builtin_amdgcn_mfma_f32_16x16x32_bf16(af, b0, acc0, 0, 0, 0);
    acc1 = __builtin_amdgcn_mfma_f32_16x16x32_bf16(af, b1v, acc1, 0, 0, 0);
  }
  int d_a = d0 + wvid * 32 + col;
  int d_b = d_a + 16;
  float bba = b2[(size_t)p * D_MODEL + d_a];
  float bbb = b2[(size_t)p * D_MODEL + d_b];
#pragma unroll
  for (int r = 0; r < 4; r++) {
    int s = quad * 4 + r;
    if (s < m) {
      size_t ro = (size_t)rows_s[s] * D_MODEL;
      out[ro + d_a] = acc0[r] + bba;
      out[ro + d_b] = acc1[r] + bbb;
    }
  }
}

// ---------------------------------------------------------------------------
extern "C" void kernel_launch(void* const* d_in, const int* in_sizes, int n_in,
                              void* d_out, int out_size, void* d_ws, size_t ws_size,
                              hipStream_t stream) {
  const float* x   = (const float*)d_in[0];
  const int*   src = (const int*)d_in[1];
  const int*   tgt = (const int*)d_in[2];
  const float* W1  = (const float*)d_in[3];
  const float* b1  = (const float*)d_in[4];
  const float* W2  = (const float*)d_in[5];
  const float* b2  = (const float*)d_in[6];
  float* out = (float*)d_out;

  // ws layout: H [1024*128] floats, then int arrays.
  float* H    = (float*)d_ws;
  int* perm   = (int*)(H + (size_t)BATCH * ADAPT);
  int* cpair  = perm + BATCH;
  int* cbase  = cpair + NSLOT;
  int* cmarr  = cbase + NSLOT;

  bucket_k<<<1, 1024, 0, stream>>>(src, tgt, perm, cpair, cbase, cmarr);
  gemm1_k<<<dim3(NSLOT, 2), 256, 0, stream>>>(x, W1, b1, perm, cpair, cbase, cmarr, H);
  gemm2_k<<<dim3(NSLOT, 8), 256, 0, stream>>>(x, W2, b2, perm, cpair, cbase, cmarr, H, out);
  (void)in_sizes; (void)n_in; (void)out_size; (void)ws_size;
}

// Round 3
// 126.364 us; speedup vs baseline: 1.1075x; 1.1075x over previous
//
#include <hip/hip_runtime.h>

#define D_MODEL 1024
#define ADAPT   128
#define NUM_LIB 8
#define BATCH   1024
#define CH      16
#define NSLOT   128

typedef __attribute__((ext_vector_type(8))) short bf16x8;
typedef __attribute__((ext_vector_type(4))) float f32x4;

__device__ __forceinline__ short f2bf(float f) {
  unsigned u = __float_as_uint(f);
  u += 0x7FFFu + ((u >> 16) & 1u);   // RNE to bf16
  return (short)(u >> 16);
}

// ---------------------------------------------------------------------------
// Kernel 1: bucket samples by pair, build CSR perm + chunk table in ws.
// ---------------------------------------------------------------------------
__global__ __launch_bounds__(1024) void bucket_k(const int* __restrict__ src,
                                                 const int* __restrict__ tgt,
                                                 int* __restrict__ perm,
                                                 int* __restrict__ cpair,
                                                 int* __restrict__ cbase,
                                                 int* __restrict__ cm) {
  __shared__ int cnt[64];
  __shared__ int offs[64];
  __shared__ int pos[64];
  __shared__ int choff[65];
  int t = threadIdx.x;
  if (t < 64) { cnt[t] = 0; pos[t] = 0; }
  __syncthreads();
  int pair = src[t] * NUM_LIB + tgt[t];
  atomicAdd(&cnt[pair], 1);
  __syncthreads();
  if (t == 0) {
    int acc = 0, ch = 0;
    for (int i = 0; i < 64; i++) {
      offs[i] = acc; acc += cnt[i];
      choff[i] = ch; ch += (cnt[i] + CH - 1) / CH;
    }
    choff[64] = ch;
  }
  __syncthreads();
  int sl = atomicAdd(&pos[pair], 1);
  perm[offs[pair] + sl] = t;
  if (t < 64) {                         // thread p writes pair p's chunk entries
    int nc = (cnt[t] + CH - 1) / CH, c0 = choff[t];
    for (int c = 0; c < nc; c++) {
      cpair[c0 + c] = t;
      cbase[c0 + c] = offs[t] + c * CH;
      cm[c0 + c]    = min(CH, cnt[t] - c * CH);
    }
  } else if (t < 64 + NSLOT) {          // mark unused slots empty (disjoint range)
    int slotid = t - 64;
    if (slotid >= choff[64]) cpair[slotid] = -1;
  }
}

// ---------------------------------------------------------------------------
// Kernel 2: partial H = X @ W1[p] per chunk (no bias/relu), bf16 MFMA.
// grid = (NSLOT, 2 a-halves, 2 k-halves). Partial sums go to Hp[kh].
// ---------------------------------------------------------------------------
#define BK     256
#define XS_STR 520   // 512+8 shorts (16B-granule stride 65, odd -> no conflicts)
#define WT_STR 264   // 256+8 shorts (granule stride 33, odd)

__global__ __launch_bounds__(256) void gemm1_k(const float* __restrict__ x,
                                               const float* __restrict__ W1,
                                               const int* __restrict__ perm,
                                               const int* __restrict__ cpair,
                                               const int* __restrict__ cbase,
                                               const int* __restrict__ cm,
                                               float* __restrict__ Hp) {
  int slot = blockIdx.x;
  int p = cpair[slot];
  if (p < 0 || (p % 9) == 0) return;   // empty slot or diagonal (identity)
  int m    = cm[slot];
  int base = cbase[slot];
  int a0   = blockIdx.y * 64;
  int kh   = blockIdx.z;               // k-half: [kh*512, kh*512+512)
  __shared__ int   rows_s[CH];
  __shared__ short xs[CH * XS_STR];    // X half-chunk bf16 [s][kl], kl in [0,512)
  __shared__ short wt[64 * WT_STR];    // W1 tile bf16 [a][kl'], kl' in [0,256)
  int t = threadIdx.x;
  if (t < CH) rows_s[t] = perm[base + min(t, m - 1)];
  __syncthreads();
  {  // stage X: thread (s, jg) covers k's jg*32..+31 of this k-half
    int s = t & 15, jg = t >> 4;
    const float* xr = x + (size_t)rows_s[s] * D_MODEL + kh * 512 + jg * 32;
    short* xw = xs + s * XS_STR + jg * 32;
#pragma unroll
    for (int i = 0; i < 8; i++) {
      float4 v = *(const float4*)(xr + i * 4);
      short4 o;
      o.x = f2bf(v.x); o.y = f2bf(v.y); o.z = f2bf(v.z); o.w = f2bf(v.w);
      *(short4*)(xw + i * 4) = o;
    }
  }
  int lane = t & 63, wvid = t >> 6, col = lane & 15, quad = lane >> 4;
  f32x4 acc = {0.f, 0.f, 0.f, 0.f};
  int a_st = t & 63, kg = t >> 6;      // staging role: a-lane, k-group of 64
  for (int r = 0; r < 2; r++) {
    {  // stage W1[kbase..kbase+255][a0..a0+63] -> wt[a][kl'] (transpose+cvt)
      const float* wr = W1 + ((size_t)p * D_MODEL + kh * 512 + r * BK + kg * 64) * ADAPT + a0 + a_st;
      short* ww = wt + a_st * WT_STR + kg * 64;
#pragma unroll
      for (int ii = 0; ii < 8; ii++) {
        bf16x8 o;
#pragma unroll
        for (int i = 0; i < 8; i++) o[i] = f2bf(wr[(ii * 8 + i) * ADAPT]);
        *(bf16x8*)(ww + ii * 8) = o;
      }
    }
    __syncthreads();
#pragma unroll
    for (int kk = 0; kk < 8; kk++) {
      bf16x8 af = *(const bf16x8*)(xs + col * XS_STR + r * BK + kk * 32 + quad * 8);
      bf16x8 bv = *(const bf16x8*)(wt + (wvid * 16 + col) * WT_STR + kk * 32 + quad * 8);
      acc = __builtin_amdgcn_mfma_f32_16x16x32_bf16(af, bv, acc, 0, 0, 0);
    }
    __syncthreads();
  }
  // Store raw partial (bias/relu applied in gemm2 staging).
  int a = a0 + wvid * 16 + col;
  float* Hb = Hp + (size_t)kh * BATCH * ADAPT;
#pragma unroll
  for (int r = 0; r < 4; r++) {
    int s = quad * 4 + r;
    if (s < m) Hb[(size_t)rows_s[s] * ADAPT + a] = acc[r];
  }
}

// ---------------------------------------------------------------------------
// Kernel 3: out[rows, d0..d0+127] = relu(H0+H1+b1) @ W2[p][:, d0..] + b2
// (or copy x for diagonal pairs). grid = (NSLOT, 8).
// ---------------------------------------------------------------------------
#define HS_STR  136
#define WT2_STR 136

__global__ __launch_bounds__(256) void gemm2_k(const float* __restrict__ x,
                                               const float* __restrict__ W2,
                                               const float* __restrict__ b1,
                                               const float* __restrict__ b2,
                                               const int* __restrict__ perm,
                                               const int* __restrict__ cpair,
                                               const int* __restrict__ cbase,
                                               const int* __restrict__ cm,
                                               const float* __restrict__ Hp,
                                               float* __restrict__ out) {
  int slot = blockIdx.x;
  int p = cpair[slot];
  if (p < 0) return;
  int m    = cm[slot];
  int base = cbase[slot];
  int d0   = blockIdx.y * 128;
  __shared__ int rows_s[CH];
  int t = threadIdx.x;
  if (t < CH) rows_s[t] = perm[base + min(t, m - 1)];
  __syncthreads();
  if ((p % 9) == 0) {                  // identity: exact copy x -> out
    int s = t >> 4, j = t & 15;
    if (s < m) {
      size_t off = (size_t)rows_s[s] * D_MODEL + d0 + j * 8;
      float4 v0 = *(const float4*)(x + off);
      float4 v1 = *(const float4*)(x + off + 4);
      *(float4*)(out + off)     = v0;
      *(float4*)(out + off + 4) = v1;
    }
    return;
  }
  __shared__ short hs[CH * HS_STR];     // relu(H0+H1+b1) bf16 [s][k]
  __shared__ short wt[128 * WT2_STR];   // W2 slice bf16 [d][k] (transposed)
  {  // stage H chunk: sum split-K partials + bias + relu, fp32 -> bf16
    int s = t & 15, j = t >> 4;        // k-range j*8..+7
    size_t ho = (size_t)rows_s[s] * ADAPT + j * 8;
    const float* h0 = Hp + ho;
    const float* h1 = Hp + (size_t)BATCH * ADAPT + ho;
    const float* bb = b1 + (size_t)p * ADAPT + j * 8;
    bf16x8 o;
#pragma unroll
    for (int i = 0; i < 8; i++) o[i] = f2bf(fmaxf(h0[i] + h1[i] + bb[i], 0.f));
    *(bf16x8*)(hs + s * HS_STR + j * 8) = o;
  }
  {  // stage W2[0..127][d0..d0+127] -> wt[d][k] bf16 (transpose+cvt)
    int dl = t & 127, half = t >> 7;
#pragma unroll
    for (int kgi = 0; kgi < 8; kgi++) {
      int kb = kgi * 16 + half * 8;
      const float* wr = W2 + ((size_t)p * ADAPT + kb) * D_MODEL + d0 + dl;
      bf16x8 o;
#pragma unroll
      for (int i = 0; i < 8; i++) o[i] = f2bf(wr[i * D_MODEL]);
      *(bf16x8*)(wt + dl * WT2_STR + kb) = o;
    }
  }
  __syncthreads();
  int lane = t & 63, wvid = t >> 6, col = lane & 15, quad = lane >> 4;
  f32x4 acc0 = {0.f, 0.f, 0.f, 0.f};
  f32x4 acc1 = {0.f, 0.f, 0.f, 0.f};
  // wave wvid handles d-tiles (wvid*32) and (wvid*32+16)
#pragma unroll
  for (int kk = 0; kk < 4; kk++) {
    bf16x8 af = *(const bf16x8*)(hs + col * HS_STR + kk * 32 + quad * 8);
    bf16x8 b0 = *(const bf16x8*)(wt + (wvid * 32 + col) * WT2_STR + kk * 32 + quad * 8);
    bf16x8 b1v = *(const bf16x8*)(wt + (wvid * 32 + 16 + col) * WT2_STR + kk * 32 + quad * 8);
    acc0 = __builtin_amdgcn_mfma_f32_16x16x32_bf16(af, b0, acc0, 0, 0, 0);
    acc1 = __builtin_amdgcn_mfma_f32_16x16x32_bf16(af, b1v, acc1, 0, 0, 0);
  }
  int d_a = d0 + wvid * 32 + col;
  int d_b = d_a + 16;
  float bba = b2[(size_t)p * D_MODEL + d_a];
  float bbb = b2[(size_t)p * D_MODEL + d_b];
#pragma unroll
  for (int r = 0; r < 4; r++) {
    int s = quad * 4 + r;
    if (s < m) {
      size_t ro = (size_t)rows_s[s] * D_MODEL;
      out[ro + d_a] = acc0[r] + bba;
      out[ro + d_b] = acc1[r] + bbb;
    }
  }
}

// ---------------------------------------------------------------------------
extern "C" void kernel_launch(void* const* d_in, const int* in_sizes, int n_in,
                              void* d_out, int out_size, void* d_ws, size_t ws_size,
                              hipStream_t stream) {
  const float* x   = (const float*)d_in[0];
  const int*   src = (const int*)d_in[1];
  const int*   tgt = (const int*)d_in[2];
  const float* W1  = (const float*)d_in[3];
  const float* b1  = (const float*)d_in[4];
  const float* W2  = (const float*)d_in[5];
  const float* b2  = (const float*)d_in[6];
  float* out = (float*)d_out;

  // ws layout: Hp [2][1024*128] floats (split-K partials), then int arrays.
  float* Hp   = (float*)d_ws;
  int* perm   = (int*)(Hp + 2 * (size_t)BATCH * ADAPT);
  int* cpair  = perm + BATCH;
  int* cbase  = cpair + NSLOT;
  int* cmarr  = cbase + NSLOT;

  bucket_k<<<1, 1024, 0, stream>>>(src, tgt, perm, cpair, cbase, cmarr);
  gemm1_k<<<dim3(NSLOT, 2, 2), 256, 0, stream>>>(x, W1, perm, cpair, cbase, cmarr, Hp);
  gemm2_k<<<dim3(NSLOT, 8), 256, 0, stream>>>(x, W2, b1, b2, perm, cpair, cbase, cmarr, Hp, out);
  (void)in_sizes; (void)n_in; (void)out_size; (void)ws_size;
}

// Round 4
// 122.366 us; speedup vs baseline: 1.1437x; 1.0327x over previous
//
#include <hip/hip_runtime.h>
#include <hip/hip_bf16.h>

#define D_MODEL 1024
#define ADAPT   128
#define NUM_LIB 8
#define BATCH   1024
#define CH      32
#define NSLOT   96

typedef __attribute__((ext_vector_type(8))) short bf16x8;
typedef __attribute__((ext_vector_type(4))) float f32x4;

// 2x f32 -> packed bf16 (v_cvt_pk_bf16_f32 on gfx950), RNE.
__device__ __forceinline__ unsigned pk2(float a, float b) {
  __hip_bfloat162 h = __float22bfloat162_rn(make_float2(a, b));
  return *(unsigned*)&h;
}

// ---------------------------------------------------------------------------
// Kernel 1: bucket samples by pair, build CSR perm + chunk table in ws.
// Max chunks: sum ceil(cnt/32) <= 1024/32 + 64*31/32 = 94 < NSLOT=96.
// ---------------------------------------------------------------------------
__global__ __launch_bounds__(1024) void bucket_k(const int* __restrict__ src,
                                                 const int* __restrict__ tgt,
                                                 int* __restrict__ perm,
                                                 int* __restrict__ cpair,
                                                 int* __restrict__ cbase,
                                                 int* __restrict__ cm) {
  __shared__ int cnt[64];
  __shared__ int offs[64];
  __shared__ int pos[64];
  __shared__ int choff[65];
  int t = threadIdx.x;
  if (t < 64) { cnt[t] = 0; pos[t] = 0; }
  __syncthreads();
  int pair = src[t] * NUM_LIB + tgt[t];
  atomicAdd(&cnt[pair], 1);
  __syncthreads();
  if (t == 0) {
    int acc = 0, ch = 0;
    for (int i = 0; i < 64; i++) {
      offs[i] = acc; acc += cnt[i];
      choff[i] = ch; ch += (cnt[i] + CH - 1) / CH;
    }
    choff[64] = ch;
  }
  __syncthreads();
  int sl = atomicAdd(&pos[pair], 1);
  perm[offs[pair] + sl] = t;
  if (t < 64) {                         // thread p writes pair p's chunk entries
    int nc = (cnt[t] + CH - 1) / CH, c0 = choff[t];
    for (int c = 0; c < nc; c++) {
      cpair[c0 + c] = t;
      cbase[c0 + c] = offs[t] + c * CH;
      cm[c0 + c]    = min(CH, cnt[t] - c * CH);
    }
  } else if (t < 64 + NSLOT) {          // mark unused slots empty (disjoint range)
    int slotid = t - 64;
    if (slotid >= choff[64]) cpair[slotid] = -1;
  }
}

// ---------------------------------------------------------------------------
// Kernel 2: partial H = X @ W1[p] per chunk (no bias/relu), bf16 MFMA, M=32.
// grid = (NSLOT, 2 a-halves, 2 k-halves). Partial sums go to Hp[kh].
// ---------------------------------------------------------------------------
#define BK     256
#define XS_STR 520   // 512+8 shorts; /8 = 65 granules (odd) -> b128 conflict-free
#define WT_STR 264   // 256+8 shorts; /8 = 33 (odd)

__global__ __launch_bounds__(256) void gemm1_k(const float* __restrict__ x,
                                               const float* __restrict__ W1,
                                               const int* __restrict__ perm,
                                               const int* __restrict__ cpair,
                                               const int* __restrict__ cbase,
                                               const int* __restrict__ cm,
                                               float* __restrict__ Hp) {
  int slot = blockIdx.x;
  int p = cpair[slot];
  if (p < 0 || (p % 9) == 0) return;   // empty slot or diagonal (identity)
  int m    = cm[slot];
  int base = cbase[slot];
  int a0   = blockIdx.y * 64;
  int kh   = blockIdx.z;               // k-half: [kh*512, kh*512+512)
  __shared__ int   rows_s[CH];
  __shared__ short xs[CH * XS_STR];    // X chunk bf16 [s][kl], kl in [0,512)
  __shared__ short wt[64 * WT_STR];    // W1 tile bf16 [a][kl'], kl' in [0,256)
  int t = threadIdx.x;
  if (t < CH) rows_s[t] = perm[base + min(t, m - 1)];
  __syncthreads();
  {  // stage X: thread (s = t&31, jg = t>>5) covers k's jg*64..+63 of this half
    int s = t & 31, jg = t >> 5;
    const float* xr = x + (size_t)rows_s[s] * D_MODEL + kh * 512 + jg * 64;
    uint4* xw = (uint4*)(xs + s * XS_STR + jg * 64);
#pragma unroll
    for (int i = 0; i < 8; i++) {
      float4 v0 = *(const float4*)(xr + i * 8);
      float4 v1 = *(const float4*)(xr + i * 8 + 4);
      uint4 o;
      o.x = pk2(v0.x, v0.y); o.y = pk2(v0.z, v0.w);
      o.z = pk2(v1.x, v1.y); o.w = pk2(v1.z, v1.w);
      xw[i] = o;
    }
  }
  int lane = t & 63, wvid = t >> 6, col = lane & 15, quad = lane >> 4;
  f32x4 acc0 = {0.f, 0.f, 0.f, 0.f};   // rows 0-15
  f32x4 acc1 = {0.f, 0.f, 0.f, 0.f};   // rows 16-31
  int a_st = t & 63, kg = t >> 6;      // staging role: a-lane, k-group of 64
  for (int r = 0; r < 2; r++) {
    {  // stage W1[.., a0..a0+63] -> wt[a][kl'] (transpose + pack-cvt)
      const float* wr = W1 + ((size_t)p * D_MODEL + kh * 512 + r * BK + kg * 64) * ADAPT + a0 + a_st;
      uint4* ww = (uint4*)(wt + a_st * WT_STR + kg * 64);
#pragma unroll
      for (int j8 = 0; j8 < 8; j8++) {
        uint4 o;
        o.x = pk2(wr[(j8 * 8 + 0) * ADAPT], wr[(j8 * 8 + 1) * ADAPT]);
        o.y = pk2(wr[(j8 * 8 + 2) * ADAPT], wr[(j8 * 8 + 3) * ADAPT]);
        o.z = pk2(wr[(j8 * 8 + 4) * ADAPT], wr[(j8 * 8 + 5) * ADAPT]);
        o.w = pk2(wr[(j8 * 8 + 6) * ADAPT], wr[(j8 * 8 + 7) * ADAPT]);
        ww[j8] = o;
      }
    }
    __syncthreads();
#pragma unroll
    for (int kk = 0; kk < 8; kk++) {
      bf16x8 af0 = *(const bf16x8*)(xs + col * XS_STR + r * BK + kk * 32 + quad * 8);
      bf16x8 af1 = *(const bf16x8*)(xs + (16 + col) * XS_STR + r * BK + kk * 32 + quad * 8);
      bf16x8 bv  = *(const bf16x8*)(wt + (wvid * 16 + col) * WT_STR + kk * 32 + quad * 8);
      acc0 = __builtin_amdgcn_mfma_f32_16x16x32_bf16(af0, bv, acc0, 0, 0, 0);
      acc1 = __builtin_amdgcn_mfma_f32_16x16x32_bf16(af1, bv, acc1, 0, 0, 0);
    }
    __syncthreads();
  }
  // Store raw partials (bias/relu applied in gemm2 staging).
  int a = a0 + wvid * 16 + col;
  float* Hb = Hp + (size_t)kh * BATCH * ADAPT;
#pragma unroll
  for (int r = 0; r < 4; r++) {
    int s = quad * 4 + r;
    if (s < m)      Hb[(size_t)rows_s[s] * ADAPT + a]      = acc0[r];
    if (s + 16 < m) Hb[(size_t)rows_s[s + 16] * ADAPT + a] = acc1[r];
  }
}

// ---------------------------------------------------------------------------
// Kernel 3: out[rows, d0..d0+127] = relu(H0+H1+b1) @ W2[p][:, d0..] + b2
// (or copy x for diagonal pairs). grid = (NSLOT, 8). M=32.
// ---------------------------------------------------------------------------
#define HS_STR  136
#define WT2_STR 136

__global__ __launch_bounds__(256) void gemm2_k(const float* __restrict__ x,
                                               const float* __restrict__ W2,
                                               const float* __restrict__ b1,
                                               const float* __restrict__ b2,
                                               const int* __restrict__ perm,
                                               const int* __restrict__ cpair,
                                               const int* __restrict__ cbase,
                                               const int* __restrict__ cm,
                                               const float* __restrict__ Hp,
                                               float* __restrict__ out) {
  int slot = blockIdx.x;
  int p = cpair[slot];
  if (p < 0) return;
  int m    = cm[slot];
  int base = cbase[slot];
  int d0   = blockIdx.y * 128;
  __shared__ int rows_s[CH];
  int t = threadIdx.x;
  if (t < CH) rows_s[t] = perm[base + min(t, m - 1)];
  __syncthreads();
  if ((p % 9) == 0) {                  // identity: exact copy x -> out
    int s = t >> 3, j = t & 7;         // 32 rows x 8 groups x 16 floats
    if (s < m) {
      size_t off = (size_t)rows_s[s] * D_MODEL + d0 + j * 16;
      float4 v0 = *(const float4*)(x + off);
      float4 v1 = *(const float4*)(x + off + 4);
      float4 v2 = *(const float4*)(x + off + 8);
      float4 v3 = *(const float4*)(x + off + 12);
      *(float4*)(out + off)      = v0;
      *(float4*)(out + off + 4)  = v1;
      *(float4*)(out + off + 8)  = v2;
      *(float4*)(out + off + 12) = v3;
    }
    return;
  }
  __shared__ short hs[CH * HS_STR];     // relu(H0+H1+b1) bf16 [s][k]
  __shared__ short wt[128 * WT2_STR];   // W2 slice bf16 [d][k] (transposed)
  {  // stage H chunk: sum split-K partials + bias + relu, fp32 -> bf16
    int s = t & 31, j = t >> 5;        // k-range j*16..+15
    size_t ho = (size_t)rows_s[s] * ADAPT + j * 16;
    const float* h0 = Hp + ho;
    const float* h1 = Hp + (size_t)BATCH * ADAPT + ho;
    const float* bb = b1 + (size_t)p * ADAPT + j * 16;
    uint4* hw = (uint4*)(hs + s * HS_STR + j * 16);
#pragma unroll
    for (int g = 0; g < 2; g++) {
      float v[8];
#pragma unroll
      for (int i = 0; i < 8; i++) v[i] = fmaxf(h0[g * 8 + i] + h1[g * 8 + i] + bb[g * 8 + i], 0.f);
      uint4 o;
      o.x = pk2(v[0], v[1]); o.y = pk2(v[2], v[3]);
      o.z = pk2(v[4], v[5]); o.w = pk2(v[6], v[7]);
      hw[g] = o;
    }
  }
  {  // stage W2[0..127][d0..d0+127] -> wt[d][k] bf16 (transpose + pack-cvt)
    int dl = t & 127, half = t >> 7;
#pragma unroll
    for (int kgi = 0; kgi < 8; kgi++) {
      int kb = kgi * 16 + half * 8;
      const float* wr = W2 + ((size_t)p * ADAPT + kb) * D_MODEL + d0 + dl;
      uint4 o;
      o.x = pk2(wr[0 * D_MODEL], wr[1 * D_MODEL]);
      o.y = pk2(wr[2 * D_MODEL], wr[3 * D_MODEL]);
      o.z = pk2(wr[4 * D_MODEL], wr[5 * D_MODEL]);
      o.w = pk2(wr[6 * D_MODEL], wr[7 * D_MODEL]);
      *(uint4*)(wt + dl * WT2_STR + kb) = o;
    }
  }
  __syncthreads();
  int lane = t & 63, wvid = t >> 6, col = lane & 15, quad = lane >> 4;
  f32x4 acc00 = {0.f, 0.f, 0.f, 0.f};  // rows 0-15,  d_a
  f32x4 acc01 = {0.f, 0.f, 0.f, 0.f};  // rows 0-15,  d_b
  f32x4 acc10 = {0.f, 0.f, 0.f, 0.f};  // rows 16-31, d_a
  f32x4 acc11 = {0.f, 0.f, 0.f, 0.f};  // rows 16-31, d_b
#pragma unroll
  for (int kk = 0; kk < 4; kk++) {
    bf16x8 af0 = *(const bf16x8*)(hs + col * HS_STR + kk * 32 + quad * 8);
    bf16x8 af1 = *(const bf16x8*)(hs + (16 + col) * HS_STR + kk * 32 + quad * 8);
    bf16x8 b0  = *(const bf16x8*)(wt + (wvid * 32 + col) * WT2_STR + kk * 32 + quad * 8);
    bf16x8 b1v = *(const bf16x8*)(wt + (wvid * 32 + 16 + col) * WT2_STR + kk * 32 + quad * 8);
    acc00 = __builtin_amdgcn_mfma_f32_16x16x32_bf16(af0, b0,  acc00, 0, 0, 0);
    acc01 = __builtin_amdgcn_mfma_f32_16x16x32_bf16(af0, b1v, acc01, 0, 0, 0);
    acc10 = __builtin_amdgcn_mfma_f32_16x16x32_bf16(af1, b0,  acc10, 0, 0, 0);
    acc11 = __builtin_amdgcn_mfma_f32_16x16x32_bf16(af1, b1v, acc11, 0, 0, 0);
  }
  int d_a = d0 + wvid * 32 + col;
  int d_b = d_a + 16;
  float bba = b2[(size_t)p * D_MODEL + d_a];
  float bbb = b2[(size_t)p * D_MODEL + d_b];
#pragma unroll
  for (int r = 0; r < 4; r++) {
    int s = quad * 4 + r;
    if (s < m) {
      size_t ro = (size_t)rows_s[s] * D_MODEL;
      out[ro + d_a] = acc00[r] + bba;
      out[ro + d_b] = acc01[r] + bbb;
    }
    if (s + 16 < m) {
      size_t ro = (size_t)rows_s[s + 16] * D_MODEL;
      out[ro + d_a] = acc10[r] + bba;
      out[ro + d_b] = acc11[r] + bbb;
    }
  }
}

// ---------------------------------------------------------------------------
extern "C" void kernel_launch(void* const* d_in, const int* in_sizes, int n_in,
                              void* d_out, int out_size, void* d_ws, size_t ws_size,
                              hipStream_t stream) {
  const float* x   = (const float*)d_in[0];
  const int*   src = (const int*)d_in[1];
  const int*   tgt = (const int*)d_in[2];
  const float* W1  = (const float*)d_in[3];
  const float* b1  = (const float*)d_in[4];
  const float* W2  = (const float*)d_in[5];
  const float* b2  = (const float*)d_in[6];
  float* out = (float*)d_out;

  // ws layout: Hp [2][1024*128] floats (split-K partials), then int arrays.
  float* Hp   = (float*)d_ws;
  int* perm   = (int*)(Hp + 2 * (size_t)BATCH * ADAPT);
  int* cpair  = perm + BATCH;
  int* cbase  = cpair + NSLOT;
  int* cmarr  = cbase + NSLOT;

  bucket_k<<<1, 1024, 0, stream>>>(src, tgt, perm, cpair, cbase, cmarr);
  gemm1_k<<<dim3(NSLOT, 2, 2), 256, 0, stream>>>(x, W1, perm, cpair, cbase, cmarr, Hp);
  gemm2_k<<<dim3(NSLOT, 8), 256, 0, stream>>>(x, W2, b1, b2, perm, cpair, cbase, cmarr, Hp, out);
  (void)in_sizes; (void)n_in; (void)out_size; (void)ws_size;
}

// Round 5
// 120.790 us; speedup vs baseline: 1.1586x; 1.0131x over previous
//
#include <hip/hip_runtime.h>
#include <hip/hip_bf16.h>

#define D_MODEL 1024
#define ADAPT   128
#define NUM_LIB 8
#define BATCH   1024
#define CH      32
#define NSLOT   96

typedef __attribute__((ext_vector_type(8))) short bf16x8;
typedef __attribute__((ext_vector_type(4))) float f32x4;

// 2x f32 -> packed bf16 (v_cvt_pk_bf16_f32 on gfx950), RNE.
__device__ __forceinline__ unsigned pk2(float a, float b) {
  __hip_bfloat162 h = __float22bfloat162_rn(make_float2(a, b));
  return *(unsigned*)&h;
}

// ---------------------------------------------------------------------------
// Kernel 1: bucket samples by pair, build CSR perm + chunk table in ws.
// Wave-0 shfl scan replaces the serial prefix (counts<=1024 and chunk counts
// packed into one int: low16 = count, high16 = nchunks).
// ---------------------------------------------------------------------------
__global__ __launch_bounds__(1024) void bucket_k(const int* __restrict__ src,
                                                 const int* __restrict__ tgt,
                                                 int* __restrict__ perm,
                                                 int* __restrict__ cpair,
                                                 int* __restrict__ cbase,
                                                 int* __restrict__ cm) {
  __shared__ int cnt[64];
  __shared__ int offs[64];
  __shared__ int pos[64];
  __shared__ int choff[65];
  int t = threadIdx.x;
  if (t < 64) { cnt[t] = 0; pos[t] = 0; }
  __syncthreads();
  int pair = src[t] * NUM_LIB + tgt[t];
  atomicAdd(&cnt[pair], 1);
  __syncthreads();
  if (t < 64) {                        // exactly wave 0: parallel scan
    int c   = cnt[t];
    int nch = (c + CH - 1) >> 5;       // chunks of 32
    int v   = c | (nch << 16);
    int incl = v;
#pragma unroll
    for (int off = 1; off < 64; off <<= 1) {
      int u = __shfl_up(incl, off, 64);
      if (t >= off) incl += u;
    }
    int excl = incl - v;
    offs[t]  = excl & 0xFFFF;
    choff[t] = excl >> 16;
    if (t == 63) choff[64] = incl >> 16;
  }
  __syncthreads();
  int sl = atomicAdd(&pos[pair], 1);
  perm[offs[pair] + sl] = t;
  if (t < 64) {                         // thread p writes pair p's chunk entries
    int nc = (cnt[t] + CH - 1) >> 5, c0 = choff[t];
    for (int c = 0; c < nc; c++) {
      cpair[c0 + c] = t;
      cbase[c0 + c] = offs[t] + c * CH;
      cm[c0 + c]    = min(CH, cnt[t] - c * CH);
    }
  } else if (t < 64 + NSLOT) {          // mark unused slots empty (disjoint range)
    int slotid = t - 64;
    if (slotid >= choff[64]) cpair[slotid] = -1;
  }
}

// ---------------------------------------------------------------------------
// Kernel 2: partial H = X @ W1[p] per chunk, bf16 MFMA, M=32, split-K x4.
// grid = (NSLOT, 2 a-halves, 4 k-quarters). One staging round per block.
// ---------------------------------------------------------------------------
#define BK     256
#define XS_STR 264   // 256+8 shorts; /8 = 33 granules (odd) -> b128 conflict-free
#define WT_STR 264

__global__ __launch_bounds__(256) void gemm1_k(const float* __restrict__ x,
                                               const float* __restrict__ W1,
                                               const int* __restrict__ perm,
                                               const int* __restrict__ cpair,
                                               const int* __restrict__ cbase,
                                               const int* __restrict__ cm,
                                               float* __restrict__ Hp) {
  int slot = blockIdx.x;
  int p = cpair[slot];
  if (p < 0 || (p % 9) == 0) return;   // empty slot or diagonal (identity)
  int m    = cm[slot];
  int base = cbase[slot];
  int a0   = blockIdx.y * 64;
  int k0   = blockIdx.z * BK;          // k-quarter
  __shared__ int   rows_s[CH];
  __shared__ short xs[CH * XS_STR];    // X chunk bf16 [s][kl], kl in [0,256)
  __shared__ short wt[64 * WT_STR];    // W1 tile bf16 [a][kl]
  int t = threadIdx.x;
  int r_own = perm[base + min(t & 31, m - 1)];   // own staging row (no barrier)
  if (t < CH) rows_s[t] = perm[base + min(t, m - 1)];  // for epilogue (main barrier covers)
  {  // stage X: thread (s = t&31, jg = t>>5) covers k's jg*32..+31 of quarter
    int s = t & 31, jg = t >> 5;
    const float* xr = x + (size_t)r_own * D_MODEL + k0 + jg * 32;
    uint4* xw = (uint4*)(xs + s * XS_STR + jg * 32);
#pragma unroll
    for (int i = 0; i < 4; i++) {
      float4 v0 = *(const float4*)(xr + i * 8);
      float4 v1 = *(const float4*)(xr + i * 8 + 4);
      uint4 o;
      o.x = pk2(v0.x, v0.y); o.y = pk2(v0.z, v0.w);
      o.z = pk2(v1.x, v1.y); o.w = pk2(v1.z, v1.w);
      xw[i] = o;
    }
  }
  {  // stage W1[k0..k0+255][a0..a0+63] -> wt[a][kl] (transpose + pack-cvt)
    int a_st = t & 63, kg = t >> 6;    // a-lane, k-group of 64
    const float* wr = W1 + ((size_t)p * D_MODEL + k0 + kg * 64) * ADAPT + a0 + a_st;
    uint4* ww = (uint4*)(wt + a_st * WT_STR + kg * 64);
#pragma unroll
    for (int j8 = 0; j8 < 8; j8++) {
      uint4 o;
      o.x = pk2(wr[(j8 * 8 + 0) * ADAPT], wr[(j8 * 8 + 1) * ADAPT]);
      o.y = pk2(wr[(j8 * 8 + 2) * ADAPT], wr[(j8 * 8 + 3) * ADAPT]);
      o.z = pk2(wr[(j8 * 8 + 4) * ADAPT], wr[(j8 * 8 + 5) * ADAPT]);
      o.w = pk2(wr[(j8 * 8 + 6) * ADAPT], wr[(j8 * 8 + 7) * ADAPT]);
      ww[j8] = o;
    }
  }
  __syncthreads();
  int lane = t & 63, wvid = t >> 6, col = lane & 15, quad = lane >> 4;
  f32x4 acc0 = {0.f, 0.f, 0.f, 0.f};   // rows 0-15
  f32x4 acc1 = {0.f, 0.f, 0.f, 0.f};   // rows 16-31
#pragma unroll
  for (int kk = 0; kk < 8; kk++) {
    bf16x8 af0 = *(const bf16x8*)(xs + col * XS_STR + kk * 32 + quad * 8);
    bf16x8 af1 = *(const bf16x8*)(xs + (16 + col) * XS_STR + kk * 32 + quad * 8);
    bf16x8 bv  = *(const bf16x8*)(wt + (wvid * 16 + col) * WT_STR + kk * 32 + quad * 8);
    acc0 = __builtin_amdgcn_mfma_f32_16x16x32_bf16(af0, bv, acc0, 0, 0, 0);
    acc1 = __builtin_amdgcn_mfma_f32_16x16x32_bf16(af1, bv, acc1, 0, 0, 0);
  }
  // Store raw partials (bias/relu applied in gemm2 staging).
  int a = a0 + wvid * 16 + col;
  float* Hb = Hp + (size_t)blockIdx.z * BATCH * ADAPT;
#pragma unroll
  for (int r = 0; r < 4; r++) {
    int s = quad * 4 + r;
    if (s < m)      Hb[(size_t)rows_s[s] * ADAPT + a]      = acc0[r];
    if (s + 16 < m) Hb[(size_t)rows_s[s + 16] * ADAPT + a] = acc1[r];
  }
}

// ---------------------------------------------------------------------------
// Kernel 3: out[rows, d0..d0+63] = relu(H0+H1+H2+H3+b1) @ W2[p][:, d0..] + b2
// (or copy x for diagonal pairs). grid = (NSLOT, 16). M=32.
// ---------------------------------------------------------------------------
#define HS_STR  136
#define WT2_STR 136

__global__ __launch_bounds__(256) void gemm2_k(const float* __restrict__ x,
                                               const float* __restrict__ W2,
                                               const float* __restrict__ b1,
                                               const float* __restrict__ b2,
                                               const int* __restrict__ perm,
                                               const int* __restrict__ cpair,
                                               const int* __restrict__ cbase,
                                               const int* __restrict__ cm,
                                               const float* __restrict__ Hp,
                                               float* __restrict__ out) {
  int slot = blockIdx.x;
  int p = cpair[slot];
  if (p < 0) return;
  int m    = cm[slot];
  int base = cbase[slot];
  int d0   = blockIdx.y * 64;
  int t = threadIdx.x;
  if ((p % 9) == 0) {                  // identity: exact copy x -> out
    int s = t >> 3, j = t & 7;         // 32 rows x 8 groups x 8 floats
    int row = perm[base + min(s, m - 1)];
    if (s < m) {
      size_t off = (size_t)row * D_MODEL + d0 + j * 8;
      float4 v0 = *(const float4*)(x + off);
      float4 v1 = *(const float4*)(x + off + 4);
      *(float4*)(out + off)     = v0;
      *(float4*)(out + off + 4) = v1;
    }
    return;
  }
  __shared__ int rows_s[CH];
  __shared__ short hs[CH * HS_STR];     // relu(sum Hp + b1) bf16 [s][k]
  __shared__ short wt[64 * WT2_STR];    // W2 slice bf16 [d][k] (transposed)
  int r_own = perm[base + min(t & 31, m - 1)];
  if (t < CH) rows_s[t] = perm[base + min(t, m - 1)];
  {  // stage H chunk: sum 4 split-K partials + bias + relu, fp32 -> bf16
    int s = t & 31, j = t >> 5;        // k-range j*16..+15
    size_t ho = (size_t)r_own * ADAPT + j * 16;
    const float* h0 = Hp + ho;
    const float* bb = b1 + (size_t)p * ADAPT + j * 16;
    uint4* hw = (uint4*)(hs + s * HS_STR + j * 16);
#pragma unroll
    for (int g = 0; g < 2; g++) {
      float v[8];
#pragma unroll
      for (int i = 0; i < 8; i++) {
        float acc = bb[g * 8 + i];
#pragma unroll
        for (int q = 0; q < 4; q++) acc += h0[(size_t)q * BATCH * ADAPT + g * 8 + i];
        v[i] = fmaxf(acc, 0.f);
      }
      uint4 o;
      o.x = pk2(v[0], v[1]); o.y = pk2(v[2], v[3]);
      o.z = pk2(v[4], v[5]); o.w = pk2(v[6], v[7]);
      hw[g] = o;
    }
  }
  {  // stage W2[0..127][d0..d0+63] -> wt[d][k] bf16 (transpose + pack-cvt)
    int dl = t & 63, kg = t >> 6;      // d-lane, k-group of 32
#pragma unroll
    for (int j8 = 0; j8 < 4; j8++) {
      int kb = kg * 32 + j8 * 8;
      const float* wr = W2 + ((size_t)p * ADAPT + kb) * D_MODEL + d0 + dl;
      uint4 o;
      o.x = pk2(wr[0 * D_MODEL], wr[1 * D_MODEL]);
      o.y = pk2(wr[2 * D_MODEL], wr[3 * D_MODEL]);
      o.z = pk2(wr[4 * D_MODEL], wr[5 * D_MODEL]);
      o.w = pk2(wr[6 * D_MODEL], wr[7 * D_MODEL]);
      *(uint4*)(wt + dl * WT2_STR + kb) = o;
    }
  }
  __syncthreads();
  int lane = t & 63, wvid = t >> 6, col = lane & 15, quad = lane >> 4;
  f32x4 acc0 = {0.f, 0.f, 0.f, 0.f};   // rows 0-15
  f32x4 acc1 = {0.f, 0.f, 0.f, 0.f};   // rows 16-31
#pragma unroll
  for (int kk = 0; kk < 4; kk++) {
    bf16x8 af0 = *(const bf16x8*)(hs + col * HS_STR + kk * 32 + quad * 8);
    bf16x8 af1 = *(const bf16x8*)(hs + (16 + col) * HS_STR + kk * 32 + quad * 8);
    bf16x8 bv  = *(const bf16x8*)(wt + (wvid * 16 + col) * WT2_STR + kk * 32 + quad * 8);
    acc0 = __builtin_amdgcn_mfma_f32_16x16x32_bf16(af0, bv, acc0, 0, 0, 0);
    acc1 = __builtin_amdgcn_mfma_f32_16x16x32_bf16(af1, bv, acc1, 0, 0, 0);
  }
  int d_a = d0 + wvid * 16 + col;
  float bba = b2[(size_t)p * D_MODEL + d_a];
#pragma unroll
  for (int r = 0; r < 4; r++) {
    int s = quad * 4 + r;
    if (s < m)      out[(size_t)rows_s[s] * D_MODEL + d_a]      = acc0[r] + bba;
    if (s + 16 < m) out[(size_t)rows_s[s + 16] * D_MODEL + d_a] = acc1[r] + bba;
  }
}

// ---------------------------------------------------------------------------
extern "C" void kernel_launch(void* const* d_in, const int* in_sizes, int n_in,
                              void* d_out, int out_size, void* d_ws, size_t ws_size,
                              hipStream_t stream) {
  const float* x   = (const float*)d_in[0];
  const int*   src = (const int*)d_in[1];
  const int*   tgt = (const int*)d_in[2];
  const float* W1  = (const float*)d_in[3];
  const float* b1  = (const float*)d_in[4];
  const float* W2  = (const float*)d_in[5];
  const float* b2  = (const float*)d_in[6];
  float* out = (float*)d_out;

  // ws layout: Hp [4][1024*128] floats (split-K partials), then int arrays.
  float* Hp   = (float*)d_ws;
  int* perm   = (int*)(Hp + 4 * (size_t)BATCH * ADAPT);
  int* cpair  = perm + BATCH;
  int* cbase  = cpair + NSLOT;
  int* cmarr  = cbase + NSLOT;

  bucket_k<<<1, 1024, 0, stream>>>(src, tgt, perm, cpair, cbase, cmarr);
  gemm1_k<<<dim3(NSLOT, 2, 4), 256, 0, stream>>>(x, W1, perm, cpair, cbase, cmarr, Hp);
  gemm2_k<<<dim3(NSLOT, 16), 256, 0, stream>>>(x, W2, b1, b2, perm, cpair, cbase, cmarr, Hp, out);
  (void)in_sizes; (void)n_in; (void)out_size; (void)ws_size;
}

// Round 6
// 117.329 us; speedup vs baseline: 1.1928x; 1.0295x over previous
//
#include <hip/hip_runtime.h>
#include <hip/hip_bf16.h>

#define D_MODEL 1024
#define ADAPT   128
#define NUM_LIB 8
#define BATCH   1024
#define CH      32

typedef __attribute__((ext_vector_type(8))) short bf16x8;
typedef __attribute__((ext_vector_type(4))) float f32x4;

// 2x f32 -> packed bf16 (v_cvt_pk_bf16_f32 on gfx950), RNE.
__device__ __forceinline__ unsigned pk2(float a, float b) {
  __hip_bfloat162 h = __float22bfloat162_rn(make_float2(a, b));
  return *(unsigned*)&h;
}

// ---------------------------------------------------------------------------
// Kernel 1: partial H = X @ W1[p], bf16 MFMA, M=32, split-K x4.
// grid = (64 pairs, 2 a-halves, 4 k-quarters). Self-bucketing: each block
// scans src/tgt and builds its own row list (order irrelevant: row-keyed I/O).
// ---------------------------------------------------------------------------
#define BK     256
#define XS_STR 264   // 256+8 shorts; /8 = 33 granules (odd) -> b128 conflict-free
#define WT_STR 264

__global__ __launch_bounds__(256) void gemm1_k(const float* __restrict__ x,
                                               const float* __restrict__ W1,
                                               const int* __restrict__ src,
                                               const int* __restrict__ tgt,
                                               float* __restrict__ Hp) {
  int p = blockIdx.x;
  if ((p % 9) == 0) return;            // diagonal pair: identity path
  int a0 = blockIdx.y * 64;
  int k0 = blockIdx.z * BK;            // k-quarter
  __shared__ int   nrows;
  __shared__ int   rows_l[BATCH];
  __shared__ short xs[CH * XS_STR];    // X chunk bf16 [s][kl], kl in [0,256)
  __shared__ short wt[64 * WT_STR];    // W1 tile bf16 [a][kl]
  int t = threadIdx.x;
  if (t == 0) nrows = 0;
  __syncthreads();
  {  // self-bucket: append rows with pair==p (order irrelevant)
#pragma unroll
    for (int i = 0; i < 4; i++) {
      int s = t + 256 * i;
      int pr = src[s] * NUM_LIB + tgt[s];
      if (pr == p) rows_l[atomicAdd(&nrows, 1)] = s;
    }
  }
  {  // stage W1[k0..k0+255][a0..a0+63] -> wt[a][kl] (independent of bucketing)
    int a_st = t & 63, kg = t >> 6;    // a-lane, k-group of 64
    const float* wr = W1 + ((size_t)p * D_MODEL + k0 + kg * 64) * ADAPT + a0 + a_st;
    uint4* ww = (uint4*)(wt + a_st * WT_STR + kg * 64);
#pragma unroll
    for (int j8 = 0; j8 < 8; j8++) {
      uint4 o;
      o.x = pk2(wr[(j8 * 8 + 0) * ADAPT], wr[(j8 * 8 + 1) * ADAPT]);
      o.y = pk2(wr[(j8 * 8 + 2) * ADAPT], wr[(j8 * 8 + 3) * ADAPT]);
      o.z = pk2(wr[(j8 * 8 + 4) * ADAPT], wr[(j8 * 8 + 5) * ADAPT]);
      o.w = pk2(wr[(j8 * 8 + 6) * ADAPT], wr[(j8 * 8 + 7) * ADAPT]);
      ww[j8] = o;
    }
  }
  __syncthreads();                     // covers bucketing + wt staging
  int n = nrows;
  if (n == 0) return;
  int lane = t & 63, wvid = t >> 6, col = lane & 15, quad = lane >> 4;
  float* Hb = Hp + (size_t)blockIdx.z * BATCH * ADAPT;
  for (int c0 = 0; c0 < n; c0 += CH) {
    int m = min(CH, n - c0);
    {  // stage X chunk: thread (s=t&31, jg=t>>5) covers k's jg*32..+31
      int s = t & 31, jg = t >> 5;
      int row = rows_l[c0 + min(s, m - 1)];
      const float* xr = x + (size_t)row * D_MODEL + k0 + jg * 32;
      uint4* xw = (uint4*)(xs + s * XS_STR + jg * 32);
#pragma unroll
      for (int i = 0; i < 4; i++) {
        float4 v0 = *(const float4*)(xr + i * 8);
        float4 v1 = *(const float4*)(xr + i * 8 + 4);
        uint4 o;
        o.x = pk2(v0.x, v0.y); o.y = pk2(v0.z, v0.w);
        o.z = pk2(v1.x, v1.y); o.w = pk2(v1.z, v1.w);
        xw[i] = o;
      }
    }
    __syncthreads();
    f32x4 acc0 = {0.f, 0.f, 0.f, 0.f};   // rows 0-15
    f32x4 acc1 = {0.f, 0.f, 0.f, 0.f};   // rows 16-31
#pragma unroll
    for (int kk = 0; kk < 8; kk++) {
      bf16x8 af0 = *(const bf16x8*)(xs + col * XS_STR + kk * 32 + quad * 8);
      bf16x8 af1 = *(const bf16x8*)(xs + (16 + col) * XS_STR + kk * 32 + quad * 8);
      bf16x8 bv  = *(const bf16x8*)(wt + (wvid * 16 + col) * WT_STR + kk * 32 + quad * 8);
      acc0 = __builtin_amdgcn_mfma_f32_16x16x32_bf16(af0, bv, acc0, 0, 0, 0);
      acc1 = __builtin_amdgcn_mfma_f32_16x16x32_bf16(af1, bv, acc1, 0, 0, 0);
    }
    int a = a0 + wvid * 16 + col;
#pragma unroll
    for (int r = 0; r < 4; r++) {
      int s2 = quad * 4 + r;
      if (s2 < m)      Hb[(size_t)rows_l[c0 + s2] * ADAPT + a]      = acc0[r];
      if (s2 + 16 < m) Hb[(size_t)rows_l[c0 + s2 + 16] * ADAPT + a] = acc1[r];
    }
    if (c0 + CH < n) __syncthreads();  // protect xs before next chunk's staging
  }
}

// ---------------------------------------------------------------------------
// Kernel 2: out[rows, d0..d0+127] = relu(sum Hp + b1) @ W2[p][:, d0..] + b2
// (or copy x for diagonal pairs). grid = (64 pairs, 8 d-slices). M=32.
// ---------------------------------------------------------------------------
#define HS_STR  136
#define WT2_STR 136

__global__ __launch_bounds__(256) void gemm2_k(const float* __restrict__ x,
                                               const float* __restrict__ W2,
                                               const float* __restrict__ b1,
                                               const float* __restrict__ b2,
                                               const int* __restrict__ src,
                                               const int* __restrict__ tgt,
                                               const float* __restrict__ Hp,
                                               float* __restrict__ out) {
  int p = blockIdx.x;
  int d0 = blockIdx.y * 128;
  __shared__ int nrows;
  __shared__ int rows_l[BATCH];
  int t = threadIdx.x;
  if (t == 0) nrows = 0;
  __syncthreads();
  {  // self-bucket
#pragma unroll
    for (int i = 0; i < 4; i++) {
      int s = t + 256 * i;
      int pr = src[s] * NUM_LIB + tgt[s];
      if (pr == p) rows_l[atomicAdd(&nrows, 1)] = s;
    }
  }
  if ((p % 9) == 0) {                  // identity: exact copy x -> out
    __syncthreads();
    int n = nrows;
    int j = t & 7;                     // 8 threads/row x 16 floats
    for (int c = t >> 3; c < n; c += 32) {
      size_t off = (size_t)rows_l[c] * D_MODEL + d0 + j * 16;
      float4 v0 = *(const float4*)(x + off);
      float4 v1 = *(const float4*)(x + off + 4);
      float4 v2 = *(const float4*)(x + off + 8);
      float4 v3 = *(const float4*)(x + off + 12);
      *(float4*)(out + off)      = v0;
      *(float4*)(out + off + 4)  = v1;
      *(float4*)(out + off + 8)  = v2;
      *(float4*)(out + off + 12) = v3;
    }
    return;
  }
  __shared__ short hs[CH * HS_STR];     // relu(sum Hp + b1) bf16 [s][k]
  __shared__ short wt[128 * WT2_STR];   // W2 slice bf16 [d][k] (transposed)
  {  // stage W2[0..127][d0..d0+127] -> wt[d][k] (independent of bucketing)
    int dl = t & 127, half = t >> 7;
#pragma unroll
    for (int kgi = 0; kgi < 8; kgi++) {
      int kb = kgi * 16 + half * 8;
      const float* wr = W2 + ((size_t)p * ADAPT + kb) * D_MODEL + d0 + dl;
      uint4 o;
      o.x = pk2(wr[0 * D_MODEL], wr[1 * D_MODEL]);
      o.y = pk2(wr[2 * D_MODEL], wr[3 * D_MODEL]);
      o.z = pk2(wr[4 * D_MODEL], wr[5 * D_MODEL]);
      o.w = pk2(wr[6 * D_MODEL], wr[7 * D_MODEL]);
      *(uint4*)(wt + dl * WT2_STR + kb) = o;
    }
  }
  __syncthreads();                     // covers bucketing + wt staging
  int n = nrows;
  if (n == 0) return;
  int lane = t & 63, wvid = t >> 6, col = lane & 15, quad = lane >> 4;
  for (int c0 = 0; c0 < n; c0 += CH) {
    int m = min(CH, n - c0);
    {  // stage H chunk: sum 4 split-K partials + bias + relu, fp32 -> bf16
      int s = t & 31, j = t >> 5;      // k-range j*16..+15
      int row = rows_l[c0 + min(s, m - 1)];
      size_t ho = (size_t)row * ADAPT + j * 16;
      const float* bb = b1 + (size_t)p * ADAPT + j * 16;
      uint4* hw = (uint4*)(hs + s * HS_STR + j * 16);
#pragma unroll
      for (int g = 0; g < 2; g++) {
        float v[8];
#pragma unroll
        for (int i = 0; i < 8; i++) {
          float acc = bb[g * 8 + i];
#pragma unroll
          for (int q = 0; q < 4; q++) acc += Hp[(size_t)q * BATCH * ADAPT + ho + g * 8 + i];
          v[i] = fmaxf(acc, 0.f);
        }
        uint4 o;
        o.x = pk2(v[0], v[1]); o.y = pk2(v[2], v[3]);
        o.z = pk2(v[4], v[5]); o.w = pk2(v[6], v[7]);
        hw[g] = o;
      }
    }
    __syncthreads();
    f32x4 acc00 = {0.f, 0.f, 0.f, 0.f};  // rows 0-15,  d_a
    f32x4 acc01 = {0.f, 0.f, 0.f, 0.f};  // rows 0-15,  d_b
    f32x4 acc10 = {0.f, 0.f, 0.f, 0.f};  // rows 16-31, d_a
    f32x4 acc11 = {0.f, 0.f, 0.f, 0.f};  // rows 16-31, d_b
#pragma unroll
    for (int kk = 0; kk < 4; kk++) {
      bf16x8 af0 = *(const bf16x8*)(hs + col * HS_STR + kk * 32 + quad * 8);
      bf16x8 af1 = *(const bf16x8*)(hs + (16 + col) * HS_STR + kk * 32 + quad * 8);
      bf16x8 b0  = *(const bf16x8*)(wt + (wvid * 32 + col) * WT2_STR + kk * 32 + quad * 8);
      bf16x8 b1v = *(const bf16x8*)(wt + (wvid * 32 + 16 + col) * WT2_STR + kk * 32 + quad * 8);
      acc00 = __builtin_amdgcn_mfma_f32_16x16x32_bf16(af0, b0,  acc00, 0, 0, 0);
      acc01 = __builtin_amdgcn_mfma_f32_16x16x32_bf16(af0, b1v, acc01, 0, 0, 0);
      acc10 = __builtin_amdgcn_mfma_f32_16x16x32_bf16(af1, b0,  acc10, 0, 0, 0);
      acc11 = __builtin_amdgcn_mfma_f32_16x16x32_bf16(af1, b1v, acc11, 0, 0, 0);
    }
    int d_a = d0 + wvid * 32 + col;
    int d_b = d_a + 16;
    float bba = b2[(size_t)p * D_MODEL + d_a];
    float bbb = b2[(size_t)p * D_MODEL + d_b];
#pragma unroll
    for (int r = 0; r < 4; r++) {
      int s2 = quad * 4 + r;
      if (s2 < m) {
        size_t ro = (size_t)rows_l[c0 + s2] * D_MODEL;
        out[ro + d_a] = acc00[r] + bba;
        out[ro + d_b] = acc01[r] + bbb;
      }
      if (s2 + 16 < m) {
        size_t ro = (size_t)rows_l[c0 + s2 + 16] * D_MODEL;
        out[ro + d_a] = acc10[r] + bba;
        out[ro + d_b] = acc11[r] + bbb;
      }
    }
    if (c0 + CH < n) __syncthreads();  // protect hs before next chunk's staging
  }
}

// ---------------------------------------------------------------------------
extern "C" void kernel_launch(void* const* d_in, const int* in_sizes, int n_in,
                              void* d_out, int out_size, void* d_ws, size_t ws_size,
                              hipStream_t stream) {
  const float* x   = (const float*)d_in[0];
  const int*   src = (const int*)d_in[1];
  const int*   tgt = (const int*)d_in[2];
  const float* W1  = (const float*)d_in[3];
  const float* b1  = (const float*)d_in[4];
  const float* W2  = (const float*)d_in[5];
  const float* b2  = (const float*)d_in[6];
  float* out = (float*)d_out;

  // ws layout: Hp [4][1024*128] floats (split-K partials).
  float* Hp = (float*)d_ws;

  gemm1_k<<<dim3(64, 2, 4), 256, 0, stream>>>(x, W1, src, tgt, Hp);
  gemm2_k<<<dim3(64, 8), 256, 0, stream>>>(x, W2, b1, b2, src, tgt, Hp, out);
  (void)in_sizes; (void)n_in; (void)out_size; (void)ws_size;
}